// Round 4
// baseline (12219.359 us; speedup 1.0000x reference)
//
#include <hip/hip_runtime.h>

#define kB 4
#define kC 128
#define kN 4096
#define kD 32
#define kL 5
#define kCO 640
#define kL2E 1.4426950408889634f

typedef float f32x4 __attribute__((ext_vector_type(4)));
typedef unsigned short u16;

__device__ __forceinline__ float bf2f(u16 u) {
  unsigned v = ((unsigned)u) << 16;
  return __builtin_bit_cast(float, v);
}
__device__ __forceinline__ u16 f2bf(float f) {
  unsigned u = __builtin_bit_cast(unsigned, f);
  u += 0x7fffu + ((u >> 16) & 1u);
  return (u16)(u >> 16);
}
// dual-dtype external load/store: f=1 -> fp32, f=0 -> bf16
__device__ __forceinline__ float ldx(const void* p, size_t i, int f) {
  return f ? ((const float*)p)[i] : bf2f(((const u16*)p)[i]);
}
__device__ __forceinline__ void stx(void* p, size_t i, int f, float v) {
  if (f) ((float*)p)[i] = v;
  else ((u16*)p)[i] = f2bf(v);
}

// ---------------- dtype probe: sample x's first 4096 u16s; bf16-real data has
// ~100% plausible bf16 exponents, fp32-read-as-u16 has ~75%. flag=1 => fp32.
__global__ void probe_kernel(const u16* __restrict__ x, int* __restrict__ flag) {
  __shared__ int red[4];
  int t = threadIdx.x;
  int cnt = 0;
#pragma unroll
  for (int k = 0; k < 16; ++k) {
    u16 u = x[t * 16 + k];
    int e = (u >> 7) & 0xFF;
    if ((e >= 64 && e <= 190) || ((u & 0x7FFF) == 0)) cnt++;
  }
#pragma unroll
  for (int o = 1; o < 64; o <<= 1) cnt += __shfl_xor(cnt, o, 64);
  int wid = t >> 6, lane = t & 63;
  if (lane == 0) red[wid] = cnt;
  __syncthreads();
  if (t == 0) {
    int total = red[0] + red[1] + red[2] + red[3];
    *flag = (total < 3686) ? 1 : 0;  // < 90% plausible => fp32
  }
}

// ---------------- sentinel (ws too small): fill out with 100+wsMB
__global__ void sentinel_kernel(void* out, float val, int total, const int* flagp) {
  int f = *flagp;
  int i = blockIdx.x * 256 + threadIdx.x;
  if (i < total) stx(out, i, f, val);
}

// ---------------- convert one external array to fp32 arena
__global__ void cvt_kernel(const void* src, float* dst, int count, const int* flagp) {
  int f = *flagp;
  int i = blockIdx.x * 256 + threadIdx.x;
  if (i < count) dst[i] = ldx(src, i, f);
}

// ---------------- xa[b][c][n] = h (+ emb)   (fp32)
__global__ __launch_bounds__(256) void prep_kernel(
    const void* h, long hstride, long hoff, const void* xyz,
    const float* __restrict__ pw, const float* __restrict__ pb, int use_emb,
    const int* flagp, float* __restrict__ xa) {
  int f = *flagp;
  int n = blockIdx.x * 256 + threadIdx.x;
  int c = blockIdx.y;
  int b = blockIdx.z;
  float v = ldx(h, (size_t)b * hstride + hoff + (size_t)c * kN + n, f);
  if (use_emb) {
    size_t xi = ((size_t)b * kN + n) * 3;
    v += pw[c * 3 + 0] * ldx(xyz, xi + 0, f) + pw[c * 3 + 1] * ldx(xyz, xi + 1, f) +
         pw[c * 3 + 2] * ldx(xyz, xi + 2, f) + pb[c];
  }
  xa[((size_t)b * kC + c) * kN + n] = v;
}

// ---------------- Q/V projection: o<32 -> Qt[b][n][32]; else Vd[b][c][n]
__global__ __launch_bounds__(256) void qv_kernel(
    const float* __restrict__ xa, const float* __restrict__ wqk,
    const float* __restrict__ wv, const float* __restrict__ bv,
    float* __restrict__ Qt, float* __restrict__ Vd) {
  int n = blockIdx.x * 256 + threadIdx.x;
  int o = blockIdx.y;
  int b = blockIdx.z;
  const float* xb = xa + (size_t)b * kC * kN + n;
  const float* w = (o < kD) ? (wqk + (size_t)o * kC) : (wv + (size_t)(o - kD) * kC);
  float s = 0.f;
#pragma unroll 8
  for (int k = 0; k < kC; ++k) s += w[k] * xb[(size_t)k * kN];
  if (o < kD) Qt[((size_t)b * kN + n) * kD + o] = s;
  else { int c = o - kD; Vd[((size_t)b * kC + c) * kN + n] = s + bv[c]; }
}

// ---------------- transpose [b][kC][N] -> [b][N][kC]
__global__ void transpose_kernel(const float* __restrict__ src, float* __restrict__ dst) {
  __shared__ float tl[32][33];
  int n0 = blockIdx.x * 32, c0 = blockIdx.y * 32, b = blockIdx.z;
  int tx = threadIdx.x & 31, ty = threadIdx.x >> 5;
#pragma unroll
  for (int i = 0; i < 4; ++i) {
    int c = c0 + ty + i * 8;
    tl[ty + i * 8][tx] = src[((size_t)b * kC + c) * kN + n0 + tx];
  }
  __syncthreads();
#pragma unroll
  for (int i = 0; i < 4; ++i) {
    int n = n0 + ty + i * 8;
    dst[((size_t)b * kN + n) * kC + c0 + tx] = tl[tx][ty + i * 8];
  }
}

// ---------------- pass1: per-row online softmax stats (fp32, exact max)
__global__ __launch_bounds__(256) void pass1_kernel(
    const float* __restrict__ Qt, float* __restrict__ rowmax, float* __restrict__ rowinv) {
  int wid = threadIdx.x >> 6, lane = threadIdx.x & 63;
  int b = blockIdx.y;
  int n = blockIdx.x * 4 + wid;
  const float* qb = Qt + (size_t)b * kN * kD;
  float qr[kD];
  {
    const f32x4* q4 = (const f32x4*)(qb + (size_t)n * kD);
#pragma unroll
    for (int k = 0; k < 8; ++k) {
      f32x4 v = q4[k];
      qr[4 * k] = v[0]; qr[4 * k + 1] = v[1]; qr[4 * k + 2] = v[2]; qr[4 * k + 3] = v[3];
    }
  }
  float mx = -3.4e38f, sm = 0.f;
  for (int it = 0; it < kN / 64; ++it) {
    int m = it * 64 + lane;
    const f32x4* qm4 = (const f32x4*)(qb + (size_t)m * kD);
    float s = 0.f;
#pragma unroll
    for (int k = 0; k < 8; ++k) {
      f32x4 v = qm4[k];
      s += v[0] * qr[4 * k] + v[1] * qr[4 * k + 1] + v[2] * qr[4 * k + 2] + v[3] * qr[4 * k + 3];
    }
    if (s > mx) { sm = sm * exp2f((mx - s) * kL2E) + 1.f; mx = s; }
    else sm += exp2f((s - mx) * kL2E);
  }
  float M = mx;
#pragma unroll
  for (int o = 1; o < 64; o <<= 1) M = fmaxf(M, __shfl_xor(M, o, 64));
  float sa = sm * exp2f((mx - M) * kL2E);
#pragma unroll
  for (int o = 1; o < 64; o <<= 1) sa += __shfl_xor(sa, o, 64);
  if (lane == 0) {
    rowmax[(size_t)b * kN + n] = M * kL2E;  // log2-space
    rowinv[(size_t)b * kN + n] = 1.f / sa;
  }
}

// ---------------- pass2: per 64-col block: recompute P, colsum, PV, write yt = xa - x_r
__global__ __launch_bounds__(256) void pass2_kernel(
    const float* __restrict__ Qt, const float* __restrict__ Vt,
    const float* __restrict__ rowmax, const float* __restrict__ rowinv,
    const float* __restrict__ xa, float* __restrict__ yt) {
  __shared__ float pl[128][65];
  __shared__ float qn[128][33];
  __shared__ float csh[64][4];
  __shared__ float invh[64];
  int t = threadIdx.x;
  int b = blockIdx.y;
  int m0 = blockIdx.x * 64;
  int m = t & 63, grp = t >> 6;
  const float* qb = Qt + (size_t)b * kN * kD;
  float qmr[32];
  {
    const f32x4* q4 = (const f32x4*)(qb + (size_t)(m0 + m) * kD);
#pragma unroll
    for (int k = 0; k < 8; ++k) {
      f32x4 v = q4[k];
      qmr[4 * k] = v[0]; qmr[4 * k + 1] = v[1]; qmr[4 * k + 2] = v[2]; qmr[4 * k + 3] = v[3];
    }
  }
  float acc[32];
#pragma unroll
  for (int i = 0; i < 32; ++i) acc[i] = 0.f;
  float cs = 0.f;
  const float* rmb = rowmax + (size_t)b * kN;
  const float* rib = rowinv + (size_t)b * kN;
  for (int nt = 0; nt < kN / 128; ++nt) {
    int n0 = nt * 128;
    __syncthreads();
    {  // load 128x32 Q rows for this n-tile
      int row = t >> 1, d0 = (t & 1) * 16;
      const float* src = qb + (size_t)(n0 + row) * kD + d0;
#pragma unroll
      for (int k = 0; k < 16; ++k) qn[row][d0 + k] = src[k];
    }
    __syncthreads();
#pragma unroll 1
    for (int j = 0; j < 32; ++j) {  // scores + P for 32 rows
      int n = grp * 32 + j;
      float s = 0.f;
#pragma unroll
      for (int d = 0; d < 32; ++d) s += qn[n][d] * qmr[d];
      float p = exp2f(s * kL2E - rmb[n0 + n]) * rib[n0 + n];
      pl[n][m] = p;
      cs += p;
    }
    __syncthreads();
    int c0 = grp * 32;
#pragma unroll 1
    for (int n = 0; n < 128; ++n) {  // acc += V[n][c0..c0+31] * p
      float pv = pl[n][m];
      const f32x4* v4 = (const f32x4*)(Vt + ((size_t)b * kN + n0 + n) * kC + c0);
#pragma unroll
      for (int k = 0; k < 8; ++k) {
        f32x4 v = v4[k];
        acc[4 * k] += v[0] * pv; acc[4 * k + 1] += v[1] * pv;
        acc[4 * k + 2] += v[2] * pv; acc[4 * k + 3] += v[3] * pv;
      }
    }
  }
  csh[m][grp] = cs;
  __syncthreads();
  if (t < 64) invh[t] = 1.f / (1e-9f + csh[t][0] + csh[t][1] + csh[t][2] + csh[t][3]);
  __syncthreads();
  float inv = invh[m];
  int c0 = grp * 32;
#pragma unroll
  for (int i = 0; i < 32; ++i) {
    size_t idx = ((size_t)b * kC + c0 + i) * kN + m0 + m;
    yt[idx] = xa[idx] - acc[i] * inv;
  }
}

// ---------------- conv1x1: dst[b][c][n] = w[c]·src[b][:][n] (+bias)
__global__ __launch_bounds__(256) void conv_kernel(
    const float* __restrict__ src, const float* __restrict__ w,
    const float* __restrict__ bias, float* __restrict__ dst) {
  int n = blockIdx.x * 256 + threadIdx.x;
  int c = blockIdx.y;
  int b = blockIdx.z;
  const float* xb = src + (size_t)b * kC * kN + n;
  const float* wr = w + (size_t)c * kC;
  float s = bias ? bias[c] : 0.f;
#pragma unroll 8
  for (int k = 0; k < kC; ++k) s += wr[k] * xb[(size_t)k * kN];
  dst[((size_t)b * kC + c) * kN + n] = s;
}

// ---------------- BN stats, TWO-PASS (avoids E[x^2]-m^2 cancellation)
__global__ __launch_bounds__(256) void bn_stats_kernel(const float* __restrict__ u,
                                                       float* __restrict__ stat) {
  int c = blockIdx.x;
  __shared__ float red[4];
  float s = 0.f;
  for (int i = threadIdx.x; i < kB * kN; i += 256) {
    int b = i >> 12, n = i & (kN - 1);
    s += u[((size_t)b * kC + c) * kN + n];
  }
#pragma unroll
  for (int o = 1; o < 64; o <<= 1) s += __shfl_xor(s, o, 64);
  int wid = threadIdx.x >> 6, lane = threadIdx.x & 63;
  if (lane == 0) red[wid] = s;
  __syncthreads();
  float mean = (red[0] + red[1] + red[2] + red[3]) / (float)(kB * kN);
  __syncthreads();
  float ss = 0.f;
  for (int i = threadIdx.x; i < kB * kN; i += 256) {
    int b = i >> 12, n = i & (kN - 1);
    float d = u[((size_t)b * kC + c) * kN + n] - mean;
    ss += d * d;
  }
#pragma unroll
  for (int o = 1; o < 64; o <<= 1) ss += __shfl_xor(ss, o, 64);
  if (lane == 0) red[wid] = ss;
  __syncthreads();
  if (threadIdx.x == 0) {
    float var = (red[0] + red[1] + red[2] + red[3]) / (float)(kB * kN);
    stat[c] = mean;
    stat[kC + c] = rsqrtf(var + 1e-5f);
  }
}

// ---------------- out = relu(BN(u)) [+ h + emb]
__global__ __launch_bounds__(256) void bn_final_kernel(
    const float* __restrict__ u, const float* __restrict__ stat,
    const float* __restrict__ g, const float* __restrict__ bb,
    const void* h, long hstride, long hoff, const void* xyz,
    const float* __restrict__ pw, const float* __restrict__ pb, int use_res,
    const int* flagp, void* out, long ostride, long ooff) {
  int f = *flagp;
  int n = blockIdx.x * 256 + threadIdx.x;
  int c = blockIdx.y;
  int b = blockIdx.z;
  float y = (u[((size_t)b * kC + c) * kN + n] - stat[c]) * stat[kC + c] * g[c] + bb[c];
  y = fmaxf(y, 0.f);
  if (use_res) {
    size_t xi = ((size_t)b * kN + n) * 3;
    float e = pw[c * 3 + 0] * ldx(xyz, xi + 0, f) + pw[c * 3 + 1] * ldx(xyz, xi + 1, f) +
              pw[c * 3 + 2] * ldx(xyz, xi + 2, f) + pb[c];
    y += ldx(h, (size_t)b * hstride + hoff + (size_t)c * kN + n, f) + e;
  }
  stx(out, (size_t)b * ostride + ooff + (size_t)c * kN + n, f, y);
}

extern "C" void kernel_launch(void* const* d_in, const int* in_sizes, int n_in,
                              void* d_out, int out_size, void* d_ws, size_t ws_size,
                              hipStream_t stream) {
  const void* x = d_in[0];
  const void* xyz = d_in[1];
  char* ws = (char*)d_ws;
  const size_t MB = (size_t)1 << 20;

  int* flag = (int*)ws;  // [0, 4KB)
  probe_kernel<<<dim3(1), dim3(256), 0, stream>>>((const u16*)x, flag);

  const size_t NEED = 28 * MB;
  if (ws_size < NEED) {
    float val = 100.0f + (float)(ws_size >> 20);
    sentinel_kernel<<<dim3((out_size + 255) / 256), dim3(256), 0, stream>>>(
        d_out, val, out_size, flag);
    return;
  }

  // fp32 weight arena [4KB, 1MB)
  float* wf = (float*)(ws + 4096);
  size_t off = 0;
  float* w_conv1 = wf + off; off += 16384;
  float* w_bn1g = wf + off; off += 128;
  float* w_bn1b = wf + off; off += 128;
  float* w_posw = wf + off; off += 384;
  float* w_posb = wf + off; off += 128;
  float* w_wqk = wf + off; off += (size_t)kL * kD * kC;   // 20480
  float* w_wv = wf + off; off += (size_t)kL * kC * kC;    // 81920
  float* w_bv = wf + off; off += (size_t)kL * kC;         // 640
  float* w_wt = wf + off; off += (size_t)kL * kC * kC;    // 81920
  float* w_bt = wf + off; off += (size_t)kL * kC;
  float* w_bng = wf + off; off += (size_t)kL * kC;
  float* w_bnb = wf + off; off += (size_t)kL * kC;

  float* xa = (float*)(ws + 1 * MB);    // [1, 9MB)  alias: u (post-pass2)
  float* u = xa;
  float* Qt = (float*)(ws + 9 * MB);    // [9, 11MB)
  float* Vt = (float*)(ws + 11 * MB);   // [11, 19MB)
  float* yt = (float*)(ws + 19 * MB);   // [19, 27MB) (also Vd staging + setup u)
  float* Vd = yt;
  float* rowmax = (float*)(ws + 27 * MB);
  float* rowinv = (float*)(ws + 27 * MB + 65536);
  float* stat = (float*)(ws + 27 * MB + 131072);

  dim3 blk(256);

  // convert weights to fp32 arena
  struct { const void* s; float* d; int n; } cv[12] = {
      {d_in[2], w_conv1, 16384}, {d_in[3], w_bn1g, 128}, {d_in[4], w_bn1b, 128},
      {d_in[5], w_posw, 384},    {d_in[6], w_posb, 128}, {d_in[7], w_wqk, 20480},
      {d_in[8], w_wv, 81920},    {d_in[9], w_bv, 640},   {d_in[10], w_wt, 81920},
      {d_in[11], w_bt, 640},     {d_in[12], w_bng, 640}, {d_in[13], w_bnb, 640}};
  for (int i = 0; i < 12; ++i)
    cvt_kernel<<<dim3((cv[i].n + 255) / 256), blk, 0, stream>>>(cv[i].s, cv[i].d, cv[i].n, flag);

  long sbo = (long)kCO * kN;
  long h0off = (long)4 * kC * kN;  // setup h parked in (not-yet-written) layer-4 slice

  // ---- setup: conv1 + BN + relu -> h0
  prep_kernel<<<dim3(kN / 256, kC, kB), blk, 0, stream>>>(
      x, (long)kC * kN, 0, xyz, w_posw, w_posb, 0, flag, xa);
  conv_kernel<<<dim3(kN / 256, kC, kB), blk, 0, stream>>>(xa, w_conv1, nullptr, yt);
  bn_stats_kernel<<<dim3(kC), blk, 0, stream>>>(yt, stat);
  bn_final_kernel<<<dim3(kN / 256, kC, kB), blk, 0, stream>>>(
      yt, stat, w_bn1g, w_bn1b, nullptr, 0, 0, xyz, w_posw, w_posb, 0, flag,
      d_out, sbo, h0off);

  long hoff = h0off;
  for (int i = 0; i < kL; ++i) {
    prep_kernel<<<dim3(kN / 256, kC, kB), blk, 0, stream>>>(
        d_out, sbo, hoff, xyz, w_posw, w_posb, 1, flag, xa);
    qv_kernel<<<dim3(kN / 256, kD + kC, kB), blk, 0, stream>>>(
        xa, w_wqk + (size_t)i * kD * kC, w_wv + (size_t)i * kC * kC,
        w_bv + (size_t)i * kC, Qt, Vd);
    transpose_kernel<<<dim3(kN / 32, kC / 32, kB), blk, 0, stream>>>(Vd, Vt);
    pass1_kernel<<<dim3(kN / 4, kB), blk, 0, stream>>>(Qt, rowmax, rowinv);
    pass2_kernel<<<dim3(kN / 64, kB), blk, 0, stream>>>(Qt, Vt, rowmax, rowinv, xa, yt);
    conv_kernel<<<dim3(kN / 256, kC, kB), blk, 0, stream>>>(
        yt, w_wt + (size_t)i * kC * kC, w_bt + (size_t)i * kC, u);
    bn_stats_kernel<<<dim3(kC), blk, 0, stream>>>(u, stat);
    bn_final_kernel<<<dim3(kN / 256, kC, kB), blk, 0, stream>>>(
        u, stat, w_bng + (size_t)i * kC, w_bnb + (size_t)i * kC,
        d_out, sbo, hoff, xyz, w_posw, w_posb, 1, flag,
        d_out, sbo, (long)i * kC * kN);
    hoff = (long)i * kC * kN;
  }
}

// Round 7
// 3437.984 us; speedup vs baseline: 3.5542x; 3.5542x over previous
//
#include <hip/hip_runtime.h>

#define kB 4
#define kC 128
#define kN 4096
#define kD 32
#define kL 5
#define kCO 640
#define kL2E 1.4426950408889634f

typedef float f32x4 __attribute__((ext_vector_type(4)));
typedef short bf16x4 __attribute__((ext_vector_type(4)));
typedef short bf16x8 __attribute__((ext_vector_type(8)));
typedef unsigned short u16;

__device__ __forceinline__ float bf2f(u16 u) {
  unsigned v = ((unsigned)u) << 16;
  return __builtin_bit_cast(float, v);
}
__device__ __forceinline__ u16 f2bf(float f) {
  unsigned u = __builtin_bit_cast(unsigned, f);
  u += 0x7fffu + ((u >> 16) & 1u);
  return (u16)(u >> 16);
}
__device__ __forceinline__ void split2(float v, u16& hi, u16& lo) {
  hi = f2bf(v);
  lo = f2bf(v - bf2f(hi));
}
// s += A*B with split operands: ah*bh + ah*bl + al*bh (drops al*bl, ~2^-16 rel)
__device__ __forceinline__ f32x4 mfma3(bf16x8 ah, bf16x8 al, bf16x8 bh, bf16x8 bl, f32x4 c) {
  c = __builtin_amdgcn_mfma_f32_16x16x32_bf16(ah, bh, c, 0, 0, 0);
  c = __builtin_amdgcn_mfma_f32_16x16x32_bf16(ah, bl, c, 0, 0, 0);
  c = __builtin_amdgcn_mfma_f32_16x16x32_bf16(al, bh, c, 0, 0, 0);
  return c;
}

// ---------------- sentinel (ws too small): encodes ws MB into output
__global__ void sentinel_kernel(float* out, float val, int total) {
  int i = blockIdx.x * 256 + threadIdx.x;
  if (i < total) out[i] = val;
}

// ---------------- split fp32 weights -> bf16 hi/lo arenas
__global__ void cvt_split_kernel(const float* __restrict__ src, u16* __restrict__ dh,
                                 u16* __restrict__ dl, int count) {
  int i = blockIdx.x * 256 + threadIdx.x;
  if (i < count) {
    u16 h, l;
    split2(src[i], h, l);
    dh[i] = h;
    dl[i] = l;
  }
}

// ---------------- xh/xl[b][n][c] = split(h[b][c][n] (+ emb))   (transpose + split)
__global__ __launch_bounds__(256) void prep_kernel(
    const float* __restrict__ h, long hstride, long hoff,
    const float* __restrict__ xyz, const float* __restrict__ pw,
    const float* __restrict__ pb, int use_emb,
    u16* __restrict__ xh, u16* __restrict__ xl) {
  __shared__ float t[32][33];
  int n0 = blockIdx.x * 32, c0 = blockIdx.y * 32, b = blockIdx.z;
  int tx = threadIdx.x & 31, ty = threadIdx.x >> 5;  // 32 x 8
  float xv0 = 0.f, xv1 = 0.f, xv2 = 0.f;
  if (use_emb) {
    const float* xp = xyz + ((size_t)b * kN + n0 + tx) * 3;
    xv0 = xp[0]; xv1 = xp[1]; xv2 = xp[2];
  }
#pragma unroll
  for (int i = 0; i < 4; ++i) {
    int c = c0 + ty + i * 8;
    float v = h[(size_t)b * hstride + hoff + (size_t)c * kN + n0 + tx];
    if (use_emb)
      v += pw[c * 3 + 0] * xv0 + pw[c * 3 + 1] * xv1 + pw[c * 3 + 2] * xv2 + pb[c];
    t[ty + i * 8][tx] = v;
  }
  __syncthreads();
#pragma unroll
  for (int i = 0; i < 4; ++i) {
    int n = n0 + ty + i * 8, c = c0 + tx;
    u16 hh, ll;
    split2(t[tx][ty + i * 8], hh, ll);
    size_t idx = ((size_t)b * kN + n) * kC + c;
    xh[idx] = hh;
    xl[idx] = ll;
  }
}

// ---------------- QV GEMM (split MFMA): Qt[b][n][32] hi/lo ; V[b][c][n] hi/lo
__global__ __launch_bounds__(256) void qv_kernel(
    const u16* __restrict__ xh, const u16* __restrict__ xl,
    const u16* __restrict__ wqkh, const u16* __restrict__ wqkl,
    const u16* __restrict__ wvh, const u16* __restrict__ wvl,
    const float* __restrict__ bv,
    u16* __restrict__ Qh, u16* __restrict__ Ql,
    u16* __restrict__ Vh, u16* __restrict__ Vl) {
  int wave = threadIdx.x >> 6, lane = threadIdx.x & 63;
  int b = blockIdx.y;
  int n0 = blockIdx.x * 64 + wave * 16;
  int col = lane & 15, g = lane >> 4;
  f32x4 acc[10] = {};
  const u16* xrh = xh + ((size_t)b * kN + n0 + col) * kC + g * 8;
  const u16* xrl = xl + ((size_t)b * kN + n0 + col) * kC + g * 8;
#pragma unroll
  for (int kk = 0; kk < 4; ++kk) {
    bf16x8 bh = *(const bf16x8*)(xrh + kk * 32);
    bf16x8 bl = *(const bf16x8*)(xrl + kk * 32);
#pragma unroll
    for (int ot = 0; ot < 10; ++ot) {
      size_t wi = (ot < 2) ? ((size_t)(ot * 16 + col) * kC) : ((size_t)((ot - 2) * 16 + col) * kC);
      const u16* wsh = (ot < 2) ? (wqkh + wi) : (wvh + wi);
      const u16* wsl = (ot < 2) ? (wqkl + wi) : (wvl + wi);
      bf16x8 ah = *(const bf16x8*)(wsh + kk * 32 + g * 8);
      bf16x8 al = *(const bf16x8*)(wsl + kk * 32 + g * 8);
      acc[ot] = mfma3(ah, al, bh, bl, acc[ot]);
    }
  }
#pragma unroll
  for (int ot = 0; ot < 2; ++ot) {
#pragma unroll
    for (int r = 0; r < 4; ++r) {
      int d = ot * 16 + 4 * g + r;
      u16 hh, ll;
      split2(acc[ot][r], hh, ll);
      size_t idx = ((size_t)b * kN + n0 + col) * kD + d;
      Qh[idx] = hh;
      Ql[idx] = ll;
    }
  }
#pragma unroll
  for (int ot = 2; ot < 10; ++ot) {
#pragma unroll
    for (int r = 0; r < 4; ++r) {
      int c = (ot - 2) * 16 + 4 * g + r;
      float v = acc[ot][r] + bv[c];
      u16 hh, ll;
      split2(v, hh, ll);
      size_t idx = ((size_t)b * kC + c) * kN + n0 + col;
      Vh[idx] = hh;
      Vl[idx] = ll;
    }
  }
}

// ---------------- pass1: fused online rowmax (log2-space) + 1/rowsum via split MFMA
__global__ __launch_bounds__(256) void pass1_kernel(
    const u16* __restrict__ Qh, const u16* __restrict__ Ql,
    float* __restrict__ rm2, float* __restrict__ rinv) {
  int wave = threadIdx.x >> 6, lane = threadIdx.x & 63;
  int b = blockIdx.y;
  int n0 = blockIdx.x * 64 + wave * 16;
  int col = lane & 15, g = lane >> 4;
  const u16* qbh = Qh + (size_t)b * kN * kD;
  const u16* qbl = Ql + (size_t)b * kN * kD;
  bf16x8 ah = *(const bf16x8*)(qbh + (size_t)(n0 + col) * kD + g * 8);
  bf16x8 al = *(const bf16x8*)(qbl + (size_t)(n0 + col) * kD + g * 8);
  float mx[4] = {-3.0e38f, -3.0e38f, -3.0e38f, -3.0e38f};
  float sm[4] = {0.f, 0.f, 0.f, 0.f};
#pragma unroll 1
  for (int m0 = 0; m0 < kN; m0 += 16) {
    bf16x8 bh = *(const bf16x8*)(qbh + (size_t)(m0 + col) * kD + g * 8);
    bf16x8 bl = *(const bf16x8*)(qbl + (size_t)(m0 + col) * kD + g * 8);
    f32x4 s = {};
    s = mfma3(ah, al, bh, bl, s);
#pragma unroll
    for (int r = 0; r < 4; ++r) {
      float nm = fmaxf(mx[r], s[r]);
      sm[r] = sm[r] * exp2f((mx[r] - nm) * kL2E) + exp2f((s[r] - nm) * kL2E);
      mx[r] = nm;
    }
  }
#pragma unroll
  for (int o = 1; o < 16; o <<= 1) {
#pragma unroll
    for (int r = 0; r < 4; ++r) {
      float Mo = __shfl_xor(mx[r], o, 64);
      float So = __shfl_xor(sm[r], o, 64);
      float nm = fmaxf(mx[r], Mo);
      sm[r] = sm[r] * exp2f((mx[r] - nm) * kL2E) + So * exp2f((Mo - nm) * kL2E);
      mx[r] = nm;
    }
  }
  if (col == 0) {
#pragma unroll
    for (int r = 0; r < 4; ++r) {
      int n = n0 + 4 * g + r;
      rm2[(size_t)b * kN + n] = mx[r] * kL2E;
      rinv[(size_t)b * kN + n] = 1.0f / sm[r];
    }
  }
}

// ---------------- pass2: yt[m][c] = x[m][c] - (V @ P[:,m]) / (eps + colsum[m])
// P split hi/lo (round-5 lesson: single-bf16 P -> BN-amplified ~1.0 error)
__global__ __launch_bounds__(256) void pass2_kernel(
    const u16* __restrict__ Qh, const u16* __restrict__ Ql,
    const u16* __restrict__ Vh, const u16* __restrict__ Vl,
    const float* __restrict__ rm2, const float* __restrict__ rinv,
    const u16* __restrict__ xh, const u16* __restrict__ xl,
    u16* __restrict__ yth, u16* __restrict__ ytl) {
  int wave = threadIdx.x >> 6, lane = threadIdx.x & 63;
  int b = blockIdx.y;
  int m0 = blockIdx.x * 64 + wave * 16;
  int col = lane & 15, g = lane >> 4;
  const u16* qbh = Qh + (size_t)b * kN * kD;
  const u16* qbl = Ql + (size_t)b * kN * kD;
  const float* rmb = rm2 + (size_t)b * kN;
  const float* rib = rinv + (size_t)b * kN;
  bf16x8 bmh = *(const bf16x8*)(qbh + (size_t)(m0 + col) * kD + g * 8);
  bf16x8 bml = *(const bf16x8*)(qbl + (size_t)(m0 + col) * kD + g * 8);
  const u16* vbh = Vh + (size_t)b * kC * kN;
  const u16* vbl = Vl + (size_t)b * kC * kN;
  f32x4 acc[8] = {};
  float cs = 0.f;
#pragma unroll 1
  for (int nn = 0; nn < kN; nn += 32) {
    bf16x8 ah0 = *(const bf16x8*)(qbh + (size_t)(nn + col) * kD + g * 8);
    bf16x8 al0 = *(const bf16x8*)(qbl + (size_t)(nn + col) * kD + g * 8);
    bf16x8 ah1 = *(const bf16x8*)(qbh + (size_t)(nn + 16 + col) * kD + g * 8);
    bf16x8 al1 = *(const bf16x8*)(qbl + (size_t)(nn + 16 + col) * kD + g * 8);
    f32x4 s0 = {}, s1 = {};
    s0 = mfma3(ah0, al0, bmh, bml, s0);
    s1 = mfma3(ah1, al1, bmh, bml, s1);
    bf16x8 b8h, b8l;
#pragma unroll
    for (int r = 0; r < 4; ++r) {
      float p0 = exp2f(s0[r] * kL2E - rmb[nn + 4 * g + r]) * rib[nn + 4 * g + r];
      float p1 = exp2f(s1[r] * kL2E - rmb[nn + 16 + 4 * g + r]) * rib[nn + 16 + 4 * g + r];
      cs += p0 + p1;
      u16 hh, ll;
      split2(p0, hh, ll);
      b8h[r] = (short)hh; b8l[r] = (short)ll;
      split2(p1, hh, ll);
      b8h[r + 4] = (short)hh; b8l[r + 4] = (short)ll;
    }
#pragma unroll
    for (int ct = 0; ct < 8; ++ct) {
      const u16* vrh = vbh + (size_t)(ct * 16 + col) * kN + nn + 4 * g;
      const u16* vrl = vbl + (size_t)(ct * 16 + col) * kN + nn + 4 * g;
      bf16x4 h0 = *(const bf16x4*)(vrh);
      bf16x4 h1 = *(const bf16x4*)(vrh + 16);
      bf16x4 l0 = *(const bf16x4*)(vrl);
      bf16x4 l1 = *(const bf16x4*)(vrl + 16);
      bf16x8 a8h = {h0[0], h0[1], h0[2], h0[3], h1[0], h1[1], h1[2], h1[3]};
      bf16x8 a8l = {l0[0], l0[1], l0[2], l0[3], l1[0], l1[1], l1[2], l1[3]};
      acc[ct] = mfma3(a8h, a8l, b8h, b8l, acc[ct]);
    }
  }
  cs += __shfl_xor(cs, 16, 64);
  cs += __shfl_xor(cs, 32, 64);
  float inv = 1.0f / (1e-9f + cs);
  const u16* xrh = xh + ((size_t)b * kN + m0 + col) * kC;
  const u16* xrl = xl + ((size_t)b * kN + m0 + col) * kC;
#pragma unroll
  for (int ct = 0; ct < 8; ++ct) {
    bf16x4 xvh = *(const bf16x4*)(xrh + ct * 16 + 4 * g);
    bf16x4 xvl = *(const bf16x4*)(xrl + ct * 16 + 4 * g);
#pragma unroll
    for (int r = 0; r < 4; ++r) {
      float xv = bf2f((u16)xvh[r]) + bf2f((u16)xvl[r]);
      float y = xv - acc[ct][r] * inv;
      u16 hh, ll;
      split2(y, hh, ll);
      size_t idx = ((size_t)b * kN + m0 + col) * kC + ct * 16 + 4 * g + r;
      yth[idx] = hh;
      ytl[idx] = ll;
    }
  }
}

// ---------------- conv GEMM (split MFMA): u[b][c][n] = w @ in (+bias), fp32 out
// u now lives in a d_out slice: strided (ustride per batch, uoff per layer)
__global__ __launch_bounds__(256) void tconv_kernel(
    const u16* __restrict__ inh, const u16* __restrict__ inl,
    const u16* __restrict__ wh, const u16* __restrict__ wl,
    const float* __restrict__ bias, float* __restrict__ u,
    long ustride, long uoff) {
  int wave = threadIdx.x >> 6, lane = threadIdx.x & 63;
  int b = blockIdx.y;
  int n0 = blockIdx.x * 64 + wave * 16;
  int col = lane & 15, g = lane >> 4;
  f32x4 acc[8] = {};
  const u16* xrh = inh + ((size_t)b * kN + n0 + col) * kC + g * 8;
  const u16* xrl = inl + ((size_t)b * kN + n0 + col) * kC + g * 8;
#pragma unroll
  for (int kk = 0; kk < 4; ++kk) {
    bf16x8 bh = *(const bf16x8*)(xrh + kk * 32);
    bf16x8 bl = *(const bf16x8*)(xrl + kk * 32);
#pragma unroll
    for (int ot = 0; ot < 8; ++ot) {
      bf16x8 ah = *(const bf16x8*)(wh + (size_t)(ot * 16 + col) * kC + kk * 32 + g * 8);
      bf16x8 al = *(const bf16x8*)(wl + (size_t)(ot * 16 + col) * kC + kk * 32 + g * 8);
      acc[ot] = mfma3(ah, al, bh, bl, acc[ot]);
    }
  }
#pragma unroll
  for (int ot = 0; ot < 8; ++ot) {
#pragma unroll
    for (int r = 0; r < 4; ++r) {
      int c = ot * 16 + 4 * g + r;
      float v = acc[ot][r] + (bias ? bias[c] : 0.f);
      u[(size_t)b * ustride + uoff + (size_t)c * kN + n0 + col] = v;
    }
  }
}

// ---------------- BN stats, two-pass fp32 (u strided in d_out)
__global__ __launch_bounds__(256) void bn_stats_kernel(const float* __restrict__ u,
                                                       long ustride, long uoff,
                                                       float* __restrict__ stat) {
  int c = blockIdx.x;
  __shared__ float red[4];
  float s = 0.f;
  for (int i = threadIdx.x; i < kB * kN; i += 256) {
    int b = i >> 12, n = i & (kN - 1);
    s += u[(size_t)b * ustride + uoff + (size_t)c * kN + n];
  }
#pragma unroll
  for (int o = 1; o < 64; o <<= 1) s += __shfl_xor(s, o, 64);
  int wid = threadIdx.x >> 6, lane = threadIdx.x & 63;
  if (lane == 0) red[wid] = s;
  __syncthreads();
  float mean = (red[0] + red[1] + red[2] + red[3]) / (float)(kB * kN);
  __syncthreads();
  float ss = 0.f;
  for (int i = threadIdx.x; i < kB * kN; i += 256) {
    int b = i >> 12, n = i & (kN - 1);
    float d = u[(size_t)b * ustride + uoff + (size_t)c * kN + n] - mean;
    ss += d * d;
  }
#pragma unroll
  for (int o = 1; o < 64; o <<= 1) ss += __shfl_xor(ss, o, 64);
  if (lane == 0) red[wid] = ss;
  __syncthreads();
  if (threadIdx.x == 0) {
    float var = (red[0] + red[1] + red[2] + red[3]) / (float)(kB * kN);
    stat[c] = mean;
    stat[kC + c] = rsqrtf(var + 1e-5f);
  }
}

// ---------------- out = relu(BN(u)) [+ h + emb]; u strided (may alias out in-place)
__global__ __launch_bounds__(256) void bn_final_kernel(
    const float* __restrict__ u, long ustride, long uoff,
    const float* __restrict__ stat,
    const float* __restrict__ g, const float* __restrict__ bb,
    const float* __restrict__ h, long hstride, long hoff,
    const float* __restrict__ xyz, const float* __restrict__ pw,
    const float* __restrict__ pb, int use_res,
    float* __restrict__ out, long ostride, long ooff) {
  int n = blockIdx.x * 256 + threadIdx.x;
  int c = blockIdx.y;
  int b = blockIdx.z;
  float y = (u[(size_t)b * ustride + uoff + (size_t)c * kN + n] - stat[c]) * stat[kC + c] * g[c] + bb[c];
  y = fmaxf(y, 0.f);
  if (use_res) {
    const float* xp = xyz + ((size_t)b * kN + n) * 3;
    float e = pw[c * 3 + 0] * xp[0] + pw[c * 3 + 1] * xp[1] + pw[c * 3 + 2] * xp[2] + pb[c];
    y += h[(size_t)b * hstride + hoff + (size_t)c * kN + n] + e;
  }
  out[(size_t)b * ostride + ooff + (size_t)c * kN + n] = y;
}

extern "C" void kernel_launch(void* const* d_in, const int* in_sizes, int n_in,
                              void* d_out, int out_size, void* d_ws, size_t ws_size,
                              hipStream_t stream) {
  const float* x = (const float*)d_in[0];
  const float* xyz = (const float*)d_in[1];
  const float* conv1_w = (const float*)d_in[2];
  const float* bn1_g = (const float*)d_in[3];
  const float* bn1_b = (const float*)d_in[4];
  const float* pos_w = (const float*)d_in[5];
  const float* pos_b = (const float*)d_in[6];
  const float* sa_wqk = (const float*)d_in[7];
  const float* sa_wv = (const float*)d_in[8];
  const float* sa_bv = (const float*)d_in[9];
  const float* sa_wt = (const float*)d_in[10];
  const float* sa_bt = (const float*)d_in[11];
  const float* sa_bng = (const float*)d_in[12];
  const float* sa_bnb = (const float*)d_in[13];
  float* out = (float*)d_out;
  char* ws = (char*)d_ws;
  const size_t MB = (size_t)1 << 20;

  const size_t NEED = 28 * MB;
  if (ws_size < NEED) {
    float val = 100.0f + (float)(ws_size >> 20);
    sentinel_kernel<<<dim3((out_size + 255) / 256), dim3(256), 0, stream>>>(out, val, out_size);
    return;
  }

  // ws buffers — every region strictly write-before-read each call, NO aliasing
  u16* xh = (u16*)(ws);                  // [0,4MB)
  u16* xl = (u16*)(ws + 4 * MB);         // [4,8MB)
  u16* yth = (u16*)(ws + 8 * MB);        // [8,12MB)
  u16* ytl = (u16*)(ws + 12 * MB);       // [12,16MB)
  u16* Vh = (u16*)(ws + 16 * MB);        // [16,20MB)
  u16* Vl = (u16*)(ws + 20 * MB);        // [20,24MB)
  u16* Qh = (u16*)(ws + 24 * MB);        // [24,25MB)
  u16* Ql = (u16*)(ws + 25 * MB);        // [25,26MB)
  u16* wa = (u16*)(ws + 26 * MB);        // weight split arena [26,27MB)
  size_t woff = 0;
  u16* c1h = wa + woff; woff += 16384;
  u16* c1l = wa + woff; woff += 16384;
  u16* qkh = wa + woff; woff += 5 * 32 * 128;
  u16* qkl = wa + woff; woff += 5 * 32 * 128;
  u16* wvh = wa + woff; woff += 5 * 128 * 128;
  u16* wvl = wa + woff; woff += 5 * 128 * 128;
  u16* wth = wa + woff; woff += 5 * 128 * 128;
  u16* wtl = wa + woff; woff += 5 * 128 * 128;
  float* rm2 = (float*)(ws + 27 * MB);
  float* rinv = (float*)(ws + 27 * MB + 65536);
  float* stat = (float*)(ws + 27 * MB + 131072);

  dim3 blk(256);

  cvt_split_kernel<<<dim3(64), blk, 0, stream>>>(conv1_w, c1h, c1l, 16384);
  cvt_split_kernel<<<dim3(80), blk, 0, stream>>>(sa_wqk, qkh, qkl, 20480);
  cvt_split_kernel<<<dim3(320), blk, 0, stream>>>(sa_wv, wvh, wvl, 81920);
  cvt_split_kernel<<<dim3(320), blk, 0, stream>>>(sa_wt, wth, wtl, 81920);

  const long sbo = (long)kCO * kN;
  const long slice = (long)kC * kN;
  const long h0off = 4 * slice;  // h0 parked in layer-4 slice (dead after layer-0 reads)

  // ---- setup: conv1 + BN + relu -> h0.  u lives in out slice 0 (dead after this).
  prep_kernel<<<dim3(kN / 32, kC / 32, kB), blk, 0, stream>>>(
      x, slice, 0, xyz, pos_w, pos_b, 0, xh, xl);
  tconv_kernel<<<dim3(kN / 64, kB), blk, 0, stream>>>(
      xh, xl, c1h, c1l, nullptr, out, sbo, 0);
  bn_stats_kernel<<<dim3(kC), blk, 0, stream>>>(out, sbo, 0, stat);
  bn_final_kernel<<<dim3(kN / 256, kC, kB), blk, 0, stream>>>(
      out, sbo, 0, stat, bn1_g, bn1_b, nullptr, 0, 0, xyz, pos_w, pos_b, 0,
      out, sbo, h0off);

  long hoff = h0off;
  for (int i = 0; i < kL; ++i) {
    long uoff = (long)i * slice;  // layer-i pre-BN u lives in out slice i (in-place BN)
    prep_kernel<<<dim3(kN / 32, kC / 32, kB), blk, 0, stream>>>(
        out, sbo, hoff, xyz, pos_w, pos_b, 1, xh, xl);
    qv_kernel<<<dim3(kN / 64, kB), blk, 0, stream>>>(
        xh, xl, qkh + (size_t)i * kD * kC, qkl + (size_t)i * kD * kC,
        wvh + (size_t)i * kC * kC, wvl + (size_t)i * kC * kC,
        sa_bv + (size_t)i * kC, Qh, Ql, Vh, Vl);
    pass1_kernel<<<dim3(kN / 64, kB), blk, 0, stream>>>(Qh, Ql, rm2, rinv);
    pass2_kernel<<<dim3(kN / 64, kB), blk, 0, stream>>>(
        Qh, Ql, Vh, Vl, rm2, rinv, xh, xl, yth, ytl);
    tconv_kernel<<<dim3(kN / 64, kB), blk, 0, stream>>>(
        yth, ytl, wth + (size_t)i * kC * kC, wtl + (size_t)i * kC * kC,
        sa_bt + (size_t)i * kC, out, sbo, uoff);
    bn_stats_kernel<<<dim3(kC), blk, 0, stream>>>(out, sbo, uoff, stat);
    bn_final_kernel<<<dim3(kN / 256, kC, kB), blk, 0, stream>>>(
        out, sbo, uoff, stat, sa_bng + (size_t)i * kC, sa_bnb + (size_t)i * kC,
        out, sbo, hoff, xyz, pos_w, pos_b, 1, out, sbo, uoff);
    hoff = uoff;
  }
}

// Round 8
// 3154.536 us; speedup vs baseline: 3.8736x; 1.0899x over previous
//
#include <hip/hip_runtime.h>

#define kB 4
#define kC 128
#define kN 4096
#define kD 32
#define kL 5
#define kCO 640
#define kL2E 1.4426950408889634f

typedef float f32x4 __attribute__((ext_vector_type(4)));
typedef short bf16x4 __attribute__((ext_vector_type(4)));
typedef short bf16x8 __attribute__((ext_vector_type(8)));
typedef unsigned short u16;

__device__ __forceinline__ float bf2f(u16 u) {
  unsigned v = ((unsigned)u) << 16;
  return __builtin_bit_cast(float, v);
}
__device__ __forceinline__ u16 f2bf(float f) {
  unsigned u = __builtin_bit_cast(unsigned, f);
  u += 0x7fffu + ((u >> 16) & 1u);
  return (u16)(u >> 16);
}
__device__ __forceinline__ void split2(float v, u16& hi, u16& lo) {
  hi = f2bf(v);
  lo = f2bf(v - bf2f(hi));
}
// s += A*B with split operands: ah*bh + ah*bl + al*bh (drops al*bl, ~2^-16 rel)
__device__ __forceinline__ f32x4 mfma3(bf16x8 ah, bf16x8 al, bf16x8 bh, bf16x8 bl, f32x4 c) {
  c = __builtin_amdgcn_mfma_f32_16x16x32_bf16(ah, bh, c, 0, 0, 0);
  c = __builtin_amdgcn_mfma_f32_16x16x32_bf16(ah, bl, c, 0, 0, 0);
  c = __builtin_amdgcn_mfma_f32_16x16x32_bf16(al, bh, c, 0, 0, 0);
  return c;
}

// ---------------- sentinel (ws too small): encodes ws MB into output
__global__ void sentinel_kernel(float* out, float val, int total) {
  int i = blockIdx.x * 256 + threadIdx.x;
  if (i < total) out[i] = val;
}

// ---------------- split fp32 weights -> bf16 hi/lo arenas
__global__ void cvt_split_kernel(const float* __restrict__ src, u16* __restrict__ dh,
                                 u16* __restrict__ dl, int count) {
  int i = blockIdx.x * 256 + threadIdx.x;
  if (i < count) {
    u16 h, l;
    split2(src[i], h, l);
    dh[i] = h;
    dl[i] = l;
  }
}

// ---------------- xh/xl[b][n][c] = split(h[b][c][n] (+ emb))   (transpose + split)
__global__ __launch_bounds__(256) void prep_kernel(
    const float* __restrict__ h, long hstride, long hoff,
    const float* __restrict__ xyz, const float* __restrict__ pw,
    const float* __restrict__ pb, int use_emb,
    u16* __restrict__ xh, u16* __restrict__ xl) {
  __shared__ float t[32][33];
  int n0 = blockIdx.x * 32, c0 = blockIdx.y * 32, b = blockIdx.z;
  int tx = threadIdx.x & 31, ty = threadIdx.x >> 5;  // 32 x 8
  float xv0 = 0.f, xv1 = 0.f, xv2 = 0.f;
  if (use_emb) {
    const float* xp = xyz + ((size_t)b * kN + n0 + tx) * 3;
    xv0 = xp[0]; xv1 = xp[1]; xv2 = xp[2];
  }
#pragma unroll
  for (int i = 0; i < 4; ++i) {
    int c = c0 + ty + i * 8;
    float v = h[(size_t)b * hstride + hoff + (size_t)c * kN + n0 + tx];
    if (use_emb)
      v += pw[c * 3 + 0] * xv0 + pw[c * 3 + 1] * xv1 + pw[c * 3 + 2] * xv2 + pb[c];
    t[ty + i * 8][tx] = v;
  }
  __syncthreads();
#pragma unroll
  for (int i = 0; i < 4; ++i) {
    int n = n0 + ty + i * 8, c = c0 + tx;
    u16 hh, ll;
    split2(t[tx][ty + i * 8], hh, ll);
    size_t idx = ((size_t)b * kN + n) * kC + c;
    xh[idx] = hh;
    xl[idx] = ll;
  }
}

// ---------------- QV GEMM: 5 waves x 2 output-tiles, 16 n-cols per block
__global__ __launch_bounds__(320) void qv_kernel(
    const u16* __restrict__ xh, const u16* __restrict__ xl,
    const u16* __restrict__ wqkh, const u16* __restrict__ wqkl,
    const u16* __restrict__ wvh, const u16* __restrict__ wvl,
    const float* __restrict__ bv,
    u16* __restrict__ Qh, u16* __restrict__ Ql,
    u16* __restrict__ Vh, u16* __restrict__ Vl) {
  int wave = threadIdx.x >> 6, lane = threadIdx.x & 63;  // wave 0..4
  int b = blockIdx.y;
  int n0 = blockIdx.x * 16;
  int col = lane & 15, g = lane >> 4;
  f32x4 acc[2] = {};
  const u16* xrh = xh + ((size_t)b * kN + n0 + col) * kC + g * 8;
  const u16* xrl = xl + ((size_t)b * kN + n0 + col) * kC + g * 8;
#pragma unroll
  for (int kk = 0; kk < 4; ++kk) {
    bf16x8 bh = *(const bf16x8*)(xrh + kk * 32);
    bf16x8 bl = *(const bf16x8*)(xrl + kk * 32);
#pragma unroll
    for (int i = 0; i < 2; ++i) {
      int ot = wave * 2 + i;
      size_t wi = (ot < 2) ? ((size_t)(ot * 16 + col) * kC) : ((size_t)((ot - 2) * 16 + col) * kC);
      const u16* wsh = (ot < 2) ? (wqkh + wi) : (wvh + wi);
      const u16* wsl = (ot < 2) ? (wqkl + wi) : (wvl + wi);
      bf16x8 ah = *(const bf16x8*)(wsh + kk * 32 + g * 8);
      bf16x8 al = *(const bf16x8*)(wsl + kk * 32 + g * 8);
      acc[i] = mfma3(ah, al, bh, bl, acc[i]);
    }
  }
#pragma unroll
  for (int i = 0; i < 2; ++i) {
    int ot = wave * 2 + i;
    if (ot < 2) {
#pragma unroll
      for (int r = 0; r < 4; ++r) {
        int d = ot * 16 + 4 * g + r;
        u16 hh, ll;
        split2(acc[i][r], hh, ll);
        size_t idx = ((size_t)b * kN + n0 + col) * kD + d;
        Qh[idx] = hh;
        Ql[idx] = ll;
      }
    } else {
#pragma unroll
      for (int r = 0; r < 4; ++r) {
        int c = (ot - 2) * 16 + 4 * g + r;
        float v = acc[i][r] + bv[c];
        u16 hh, ll;
        split2(v, hh, ll);
        size_t idx = ((size_t)b * kC + c) * kN + n0 + col;
        Vh[idx] = hh;
        Vl[idx] = ll;
      }
    }
  }
}

// ---------------- pass1: 4 waves split the m-loop; online merge via LDS
__global__ __launch_bounds__(256) void pass1_kernel(
    const u16* __restrict__ Qh, const u16* __restrict__ Ql,
    float* __restrict__ rm2, float* __restrict__ rinv) {
  __shared__ float mxs[4][16], sms[4][16];
  int wave = threadIdx.x >> 6, lane = threadIdx.x & 63;
  int b = blockIdx.y;
  int n0 = blockIdx.x * 16;
  int col = lane & 15, g = lane >> 4;
  const u16* qbh = Qh + (size_t)b * kN * kD;
  const u16* qbl = Ql + (size_t)b * kN * kD;
  bf16x8 ah = *(const bf16x8*)(qbh + (size_t)(n0 + col) * kD + g * 8);
  bf16x8 al = *(const bf16x8*)(qbl + (size_t)(n0 + col) * kD + g * 8);
  float mx[4] = {-3.0e38f, -3.0e38f, -3.0e38f, -3.0e38f};
  float sm[4] = {0.f, 0.f, 0.f, 0.f};
#pragma unroll 1
  for (int m0 = wave * 16; m0 < kN; m0 += 64) {
    bf16x8 bh = *(const bf16x8*)(qbh + (size_t)(m0 + col) * kD + g * 8);
    bf16x8 bl = *(const bf16x8*)(qbl + (size_t)(m0 + col) * kD + g * 8);
    f32x4 s = {};
    s = mfma3(ah, al, bh, bl, s);
#pragma unroll
    for (int r = 0; r < 4; ++r) {
      float nm = fmaxf(mx[r], s[r]);
      sm[r] = sm[r] * exp2f((mx[r] - nm) * kL2E) + exp2f((s[r] - nm) * kL2E);
      mx[r] = nm;
    }
  }
#pragma unroll
  for (int o = 1; o < 16; o <<= 1) {
#pragma unroll
    for (int r = 0; r < 4; ++r) {
      float Mo = __shfl_xor(mx[r], o, 64);
      float So = __shfl_xor(sm[r], o, 64);
      float nm = fmaxf(mx[r], Mo);
      sm[r] = sm[r] * exp2f((mx[r] - nm) * kL2E) + So * exp2f((Mo - nm) * kL2E);
      mx[r] = nm;
    }
  }
  if (col == 0) {
#pragma unroll
    for (int r = 0; r < 4; ++r) {
      mxs[wave][4 * g + r] = mx[r];
      sms[wave][4 * g + r] = sm[r];
    }
  }
  __syncthreads();
  if (threadIdx.x < 16) {
    int t = threadIdx.x;
    float M = mxs[0][t], S = sms[0][t];
#pragma unroll
    for (int w = 1; w < 4; ++w) {
      float Mo = mxs[w][t], So = sms[w][t];
      float nm = fmaxf(M, Mo);
      S = S * exp2f((M - nm) * kL2E) + So * exp2f((Mo - nm) * kL2E);
      M = nm;
    }
    rm2[(size_t)b * kN + n0 + t] = M * kL2E;
    rinv[(size_t)b * kN + n0 + t] = 1.0f / S;
  }
}

// ---------------- pass2: 4 waves split the nn-loop; combine via LDS; 2 c-tiles/wave out
__global__ __launch_bounds__(256) void pass2_kernel(
    const u16* __restrict__ Qh, const u16* __restrict__ Ql,
    const u16* __restrict__ Vh, const u16* __restrict__ Vl,
    const float* __restrict__ rm2, const float* __restrict__ rinv,
    const u16* __restrict__ xh, const u16* __restrict__ xl,
    u16* __restrict__ yth, u16* __restrict__ ytl) {
  __shared__ f32x4 accs[4][8][64];
  __shared__ float csl[4][16];
  int wave = threadIdx.x >> 6, lane = threadIdx.x & 63;
  int b = blockIdx.y;
  int m0 = blockIdx.x * 16;
  int col = lane & 15, g = lane >> 4;
  const u16* qbh = Qh + (size_t)b * kN * kD;
  const u16* qbl = Ql + (size_t)b * kN * kD;
  const float* rmb = rm2 + (size_t)b * kN;
  const float* rib = rinv + (size_t)b * kN;
  bf16x8 bmh = *(const bf16x8*)(qbh + (size_t)(m0 + col) * kD + g * 8);
  bf16x8 bml = *(const bf16x8*)(qbl + (size_t)(m0 + col) * kD + g * 8);
  const u16* vbh = Vh + (size_t)b * kC * kN;
  const u16* vbl = Vl + (size_t)b * kC * kN;
  f32x4 acc[8] = {};
  float cs = 0.f;
#pragma unroll 1
  for (int nn = wave * 32; nn < kN; nn += 128) {
    bf16x8 ah0 = *(const bf16x8*)(qbh + (size_t)(nn + col) * kD + g * 8);
    bf16x8 al0 = *(const bf16x8*)(qbl + (size_t)(nn + col) * kD + g * 8);
    bf16x8 ah1 = *(const bf16x8*)(qbh + (size_t)(nn + 16 + col) * kD + g * 8);
    bf16x8 al1 = *(const bf16x8*)(qbl + (size_t)(nn + 16 + col) * kD + g * 8);
    f32x4 s0 = {}, s1 = {};
    s0 = mfma3(ah0, al0, bmh, bml, s0);
    s1 = mfma3(ah1, al1, bmh, bml, s1);
    bf16x8 b8h, b8l;
#pragma unroll
    for (int r = 0; r < 4; ++r) {
      float p0 = exp2f(s0[r] * kL2E - rmb[nn + 4 * g + r]) * rib[nn + 4 * g + r];
      float p1 = exp2f(s1[r] * kL2E - rmb[nn + 16 + 4 * g + r]) * rib[nn + 16 + 4 * g + r];
      cs += p0 + p1;
      u16 hh, ll;
      split2(p0, hh, ll);
      b8h[r] = (short)hh; b8l[r] = (short)ll;
      split2(p1, hh, ll);
      b8h[r + 4] = (short)hh; b8l[r + 4] = (short)ll;
    }
#pragma unroll
    for (int ct = 0; ct < 8; ++ct) {
      const u16* vrh = vbh + (size_t)(ct * 16 + col) * kN + nn + 4 * g;
      const u16* vrl = vbl + (size_t)(ct * 16 + col) * kN + nn + 4 * g;
      bf16x4 h0 = *(const bf16x4*)(vrh);
      bf16x4 h1 = *(const bf16x4*)(vrh + 16);
      bf16x4 l0 = *(const bf16x4*)(vrl);
      bf16x4 l1 = *(const bf16x4*)(vrl + 16);
      bf16x8 a8h = {h0[0], h0[1], h0[2], h0[3], h1[0], h1[1], h1[2], h1[3]};
      bf16x8 a8l = {l0[0], l0[1], l0[2], l0[3], l1[0], l1[1], l1[2], l1[3]};
      acc[ct] = mfma3(a8h, a8l, b8h, b8l, acc[ct]);
    }
  }
  cs += __shfl_xor(cs, 16, 64);
  cs += __shfl_xor(cs, 32, 64);
#pragma unroll
  for (int ct = 0; ct < 8; ++ct) accs[wave][ct][lane] = acc[ct];
  if (lane < 16) csl[wave][lane] = cs;
  __syncthreads();
  float csum = csl[0][col] + csl[1][col] + csl[2][col] + csl[3][col];
  float inv = 1.0f / (1e-9f + csum);
  const u16* xrh = xh + ((size_t)b * kN + m0 + col) * kC;
  const u16* xrl = xl + ((size_t)b * kN + m0 + col) * kC;
#pragma unroll
  for (int i = 0; i < 2; ++i) {
    int ct = wave * 2 + i;
    f32x4 a = accs[0][ct][lane];
    a += accs[1][ct][lane];
    a += accs[2][ct][lane];
    a += accs[3][ct][lane];
    bf16x4 xvh = *(const bf16x4*)(xrh + ct * 16 + 4 * g);
    bf16x4 xvl = *(const bf16x4*)(xrl + ct * 16 + 4 * g);
#pragma unroll
    for (int r = 0; r < 4; ++r) {
      float xv = bf2f((u16)xvh[r]) + bf2f((u16)xvl[r]);
      float y = xv - a[r] * inv;
      u16 hh, ll;
      split2(y, hh, ll);
      size_t idx = ((size_t)b * kN + m0 + col) * kC + ct * 16 + 4 * g + r;
      yth[idx] = hh;
      ytl[idx] = ll;
    }
  }
}

// ---------------- conv GEMM: 4 waves x 2 output-tiles, 16 n-cols per block
__global__ __launch_bounds__(256) void tconv_kernel(
    const u16* __restrict__ inh, const u16* __restrict__ inl,
    const u16* __restrict__ wh, const u16* __restrict__ wl,
    const float* __restrict__ bias, float* __restrict__ u,
    long ustride, long uoff) {
  int wave = threadIdx.x >> 6, lane = threadIdx.x & 63;
  int b = blockIdx.y;
  int n0 = blockIdx.x * 16;
  int col = lane & 15, g = lane >> 4;
  f32x4 acc[2] = {};
  const u16* xrh = inh + ((size_t)b * kN + n0 + col) * kC + g * 8;
  const u16* xrl = inl + ((size_t)b * kN + n0 + col) * kC + g * 8;
#pragma unroll
  for (int kk = 0; kk < 4; ++kk) {
    bf16x8 bh = *(const bf16x8*)(xrh + kk * 32);
    bf16x8 bl = *(const bf16x8*)(xrl + kk * 32);
#pragma unroll
    for (int i = 0; i < 2; ++i) {
      int ot = wave * 2 + i;
      bf16x8 ah = *(const bf16x8*)(wh + (size_t)(ot * 16 + col) * kC + kk * 32 + g * 8);
      bf16x8 al = *(const bf16x8*)(wl + (size_t)(ot * 16 + col) * kC + kk * 32 + g * 8);
      acc[i] = mfma3(ah, al, bh, bl, acc[i]);
    }
  }
#pragma unroll
  for (int i = 0; i < 2; ++i) {
    int ot = wave * 2 + i;
#pragma unroll
    for (int r = 0; r < 4; ++r) {
      int c = ot * 16 + 4 * g + r;
      float v = acc[i][r] + (bias ? bias[c] : 0.f);
      u[(size_t)b * ustride + uoff + (size_t)c * kN + n0 + col] = v;
    }
  }
}

// ---------------- BN stats, two-pass fp32 (u strided in d_out)
__global__ __launch_bounds__(256) void bn_stats_kernel(const float* __restrict__ u,
                                                       long ustride, long uoff,
                                                       float* __restrict__ stat) {
  int c = blockIdx.x;
  __shared__ float red[4];
  float s = 0.f;
  for (int i = threadIdx.x; i < kB * kN; i += 256) {
    int b = i >> 12, n = i & (kN - 1);
    s += u[(size_t)b * ustride + uoff + (size_t)c * kN + n];
  }
#pragma unroll
  for (int o = 1; o < 64; o <<= 1) s += __shfl_xor(s, o, 64);
  int wid = threadIdx.x >> 6, lane = threadIdx.x & 63;
  if (lane == 0) red[wid] = s;
  __syncthreads();
  float mean = (red[0] + red[1] + red[2] + red[3]) / (float)(kB * kN);
  __syncthreads();
  float ss = 0.f;
  for (int i = threadIdx.x; i < kB * kN; i += 256) {
    int b = i >> 12, n = i & (kN - 1);
    float d = u[(size_t)b * ustride + uoff + (size_t)c * kN + n] - mean;
    ss += d * d;
  }
#pragma unroll
  for (int o = 1; o < 64; o <<= 1) ss += __shfl_xor(ss, o, 64);
  if (lane == 0) red[wid] = ss;
  __syncthreads();
  if (threadIdx.x == 0) {
    float var = (red[0] + red[1] + red[2] + red[3]) / (float)(kB * kN);
    stat[c] = mean;
    stat[kC + c] = rsqrtf(var + 1e-5f);
  }
}

// ---------------- out = relu(BN(u)) [+ h + emb]; u strided (may alias out in-place)
__global__ __launch_bounds__(256) void bn_final_kernel(
    const float* __restrict__ u, long ustride, long uoff,
    const float* __restrict__ stat,
    const float* __restrict__ g, const float* __restrict__ bb,
    const float* __restrict__ h, long hstride, long hoff,
    const float* __restrict__ xyz, const float* __restrict__ pw,
    const float* __restrict__ pb, int use_res,
    float* __restrict__ out, long ostride, long ooff) {
  int n = blockIdx.x * 256 + threadIdx.x;
  int c = blockIdx.y;
  int b = blockIdx.z;
  float y = (u[(size_t)b * ustride + uoff + (size_t)c * kN + n] - stat[c]) * stat[kC + c] * g[c] + bb[c];
  y = fmaxf(y, 0.f);
  if (use_res) {
    const float* xp = xyz + ((size_t)b * kN + n) * 3;
    float e = pw[c * 3 + 0] * xp[0] + pw[c * 3 + 1] * xp[1] + pw[c * 3 + 2] * xp[2] + pb[c];
    y += h[(size_t)b * hstride + hoff + (size_t)c * kN + n] + e;
  }
  out[(size_t)b * ostride + ooff + (size_t)c * kN + n] = y;
}

extern "C" void kernel_launch(void* const* d_in, const int* in_sizes, int n_in,
                              void* d_out, int out_size, void* d_ws, size_t ws_size,
                              hipStream_t stream) {
  const float* x = (const float*)d_in[0];
  const float* xyz = (const float*)d_in[1];
  const float* conv1_w = (const float*)d_in[2];
  const float* bn1_g = (const float*)d_in[3];
  const float* bn1_b = (const float*)d_in[4];
  const float* pos_w = (const float*)d_in[5];
  const float* pos_b = (const float*)d_in[6];
  const float* sa_wqk = (const float*)d_in[7];
  const float* sa_wv = (const float*)d_in[8];
  const float* sa_bv = (const float*)d_in[9];
  const float* sa_wt = (const float*)d_in[10];
  const float* sa_bt = (const float*)d_in[11];
  const float* sa_bng = (const float*)d_in[12];
  const float* sa_bnb = (const float*)d_in[13];
  float* out = (float*)d_out;
  char* ws = (char*)d_ws;
  const size_t MB = (size_t)1 << 20;

  const size_t NEED = 28 * MB;
  if (ws_size < NEED) {
    float val = 100.0f + (float)(ws_size >> 20);
    sentinel_kernel<<<dim3((out_size + 255) / 256), dim3(256), 0, stream>>>(out, val, out_size);
    return;
  }

  // ws buffers — every region strictly write-before-read each call, NO aliasing
  u16* xh = (u16*)(ws);                  // [0,4MB)
  u16* xl = (u16*)(ws + 4 * MB);         // [4,8MB)
  u16* yth = (u16*)(ws + 8 * MB);        // [8,12MB)
  u16* ytl = (u16*)(ws + 12 * MB);       // [12,16MB)
  u16* Vh = (u16*)(ws + 16 * MB);        // [16,20MB)
  u16* Vl = (u16*)(ws + 20 * MB);        // [20,24MB)
  u16* Qh = (u16*)(ws + 24 * MB);        // [24,25MB)
  u16* Ql = (u16*)(ws + 25 * MB);        // [25,26MB)
  u16* wa = (u16*)(ws + 26 * MB);        // weight split arena [26,27MB)
  size_t woff = 0;
  u16* c1h = wa + woff; woff += 16384;
  u16* c1l = wa + woff; woff += 16384;
  u16* qkh = wa + woff; woff += 5 * 32 * 128;
  u16* qkl = wa + woff; woff += 5 * 32 * 128;
  u16* wvh = wa + woff; woff += 5 * 128 * 128;
  u16* wvl = wa + woff; woff += 5 * 128 * 128;
  u16* wth = wa + woff; woff += 5 * 128 * 128;
  u16* wtl = wa + woff; woff += 5 * 128 * 128;
  float* rm2 = (float*)(ws + 27 * MB);
  float* rinv = (float*)(ws + 27 * MB + 65536);
  float* stat = (float*)(ws + 27 * MB + 131072);

  dim3 blk(256);

  cvt_split_kernel<<<dim3(64), blk, 0, stream>>>(conv1_w, c1h, c1l, 16384);
  cvt_split_kernel<<<dim3(80), blk, 0, stream>>>(sa_wqk, qkh, qkl, 20480);
  cvt_split_kernel<<<dim3(320), blk, 0, stream>>>(sa_wv, wvh, wvl, 81920);
  cvt_split_kernel<<<dim3(320), blk, 0, stream>>>(sa_wt, wth, wtl, 81920);

  const long sbo = (long)kCO * kN;
  const long slice = (long)kC * kN;
  const long h0off = 4 * slice;  // h0 parked in layer-4 slice (dead after layer-0 reads)

  // ---- setup: conv1 + BN + relu -> h0.  u lives in out slice 0 (dead after this).
  prep_kernel<<<dim3(kN / 32, kC / 32, kB), blk, 0, stream>>>(
      x, slice, 0, xyz, pos_w, pos_b, 0, xh, xl);
  tconv_kernel<<<dim3(kN / 16, kB), blk, 0, stream>>>(
      xh, xl, c1h, c1l, nullptr, out, sbo, 0);
  bn_stats_kernel<<<dim3(kC), blk, 0, stream>>>(out, sbo, 0, stat);
  bn_final_kernel<<<dim3(kN / 256, kC, kB), blk, 0, stream>>>(
      out, sbo, 0, stat, bn1_g, bn1_b, nullptr, 0, 0, xyz, pos_w, pos_b, 0,
      out, sbo, h0off);

  long hoff = h0off;
  for (int i = 0; i < kL; ++i) {
    long uoff = (long)i * slice;  // layer-i pre-BN u lives in out slice i (in-place BN)
    prep_kernel<<<dim3(kN / 32, kC / 32, kB), blk, 0, stream>>>(
        out, sbo, hoff, xyz, pos_w, pos_b, 1, xh, xl);
    qv_kernel<<<dim3(kN / 16, kB), dim3(320), 0, stream>>>(
        xh, xl, qkh + (size_t)i * kD * kC, qkl + (size_t)i * kD * kC,
        wvh + (size_t)i * kC * kC, wvl + (size_t)i * kC * kC,
        sa_bv + (size_t)i * kC, Qh, Ql, Vh, Vl);
    pass1_kernel<<<dim3(kN / 16, kB), blk, 0, stream>>>(Qh, Ql, rm2, rinv);
    pass2_kernel<<<dim3(kN / 16, kB), blk, 0, stream>>>(
        Qh, Ql, Vh, Vl, rm2, rinv, xh, xl, yth, ytl);
    tconv_kernel<<<dim3(kN / 16, kB), blk, 0, stream>>>(
        yth, ytl, wth + (size_t)i * kC * kC, wtl + (size_t)i * kC * kC,
        sa_bt + (size_t)i * kC, out, sbo, uoff);
    bn_stats_kernel<<<dim3(kC), blk, 0, stream>>>(out, sbo, uoff, stat);
    bn_final_kernel<<<dim3(kN / 256, kC, kB), blk, 0, stream>>>(
        out, sbo, uoff, stat, sa_bng + (size_t)i * kC, sa_bnb + (size_t)i * kC,
        out, sbo, hoff, xyz, pos_w, pos_b, 1, out, sbo, uoff);
    hoff = uoff;
  }
}

// Round 9
// 1347.458 us; speedup vs baseline: 9.0685x; 2.3411x over previous
//
#include <hip/hip_runtime.h>

#define kB 4
#define kC 128
#define kN 4096
#define kD 32
#define kL 5
#define kCO 640
#define kL2E 1.4426950408889634f

typedef float f32x4 __attribute__((ext_vector_type(4)));
typedef short bf16x4 __attribute__((ext_vector_type(4)));
typedef short bf16x8 __attribute__((ext_vector_type(8)));
typedef unsigned short u16;

__device__ __forceinline__ float bf2f(u16 u) {
  unsigned v = ((unsigned)u) << 16;
  return __builtin_bit_cast(float, v);
}
__device__ __forceinline__ u16 f2bf(float f) {
  unsigned u = __builtin_bit_cast(unsigned, f);
  u += 0x7fffu + ((u >> 16) & 1u);
  return (u16)(u >> 16);
}
__device__ __forceinline__ void split2(float v, u16& hi, u16& lo) {
  hi = f2bf(v);
  lo = f2bf(v - bf2f(hi));
}
// s += A*B with split operands: ah*bh + ah*bl + al*bh (drops al*bl, ~2^-16 rel)
__device__ __forceinline__ f32x4 mfma3(bf16x8 ah, bf16x8 al, bf16x8 bh, bf16x8 bl, f32x4 c) {
  c = __builtin_amdgcn_mfma_f32_16x16x32_bf16(ah, bh, c, 0, 0, 0);
  c = __builtin_amdgcn_mfma_f32_16x16x32_bf16(ah, bl, c, 0, 0, 0);
  c = __builtin_amdgcn_mfma_f32_16x16x32_bf16(al, bh, c, 0, 0, 0);
  return c;
}

// ---------------- sentinel (ws too small): encodes ws MB into output
__global__ void sentinel_kernel(float* out, float val, int total) {
  int i = blockIdx.x * 256 + threadIdx.x;
  if (i < total) out[i] = val;
}

// ---------------- split fp32 weights -> bf16 hi/lo arenas
__global__ void cvt_split_kernel(const float* __restrict__ src, u16* __restrict__ dh,
                                 u16* __restrict__ dl, int count) {
  int i = blockIdx.x * 256 + threadIdx.x;
  if (i < count) {
    u16 h, l;
    split2(src[i], h, l);
    dh[i] = h;
    dl[i] = l;
  }
}

// ---------------- xh/xl[b][n][c] = split(h[b][c][n] (+ emb))   (transpose + split)
__global__ __launch_bounds__(256) void prep_kernel(
    const float* __restrict__ h, long hstride, long hoff,
    const float* __restrict__ xyz, const float* __restrict__ pw,
    const float* __restrict__ pb, int use_emb,
    u16* __restrict__ xh, u16* __restrict__ xl) {
  __shared__ float t[32][33];
  int n0 = blockIdx.x * 32, c0 = blockIdx.y * 32, b = blockIdx.z;
  int tx = threadIdx.x & 31, ty = threadIdx.x >> 5;  // 32 x 8
  float xv0 = 0.f, xv1 = 0.f, xv2 = 0.f;
  if (use_emb) {
    const float* xp = xyz + ((size_t)b * kN + n0 + tx) * 3;
    xv0 = xp[0]; xv1 = xp[1]; xv2 = xp[2];
  }
#pragma unroll
  for (int i = 0; i < 4; ++i) {
    int c = c0 + ty + i * 8;
    float v = h[(size_t)b * hstride + hoff + (size_t)c * kN + n0 + tx];
    if (use_emb)
      v += pw[c * 3 + 0] * xv0 + pw[c * 3 + 1] * xv1 + pw[c * 3 + 2] * xv2 + pb[c];
    t[ty + i * 8][tx] = v;
  }
  __syncthreads();
#pragma unroll
  for (int i = 0; i < 4; ++i) {
    int n = n0 + ty + i * 8, c = c0 + tx;
    u16 hh, ll;
    split2(t[tx][ty + i * 8], hh, ll);
    size_t idx = ((size_t)b * kN + n) * kC + c;
    xh[idx] = hh;
    xl[idx] = ll;
  }
}

// ---------------- QV GEMM: 5 waves x 2 tiles, 16 n-cols per block.
// V written in FRAGMENT-PACKED layout: Vp[b][nt=n/32][ct=c/16][lane][8 bf16],
// lane=(g<<4)|col holds V[ct*16+col][nt*32+4g..+3] (bytes 0-7, part p=0)
// and V[ct*16+col][nt*32+16+4g..+3] (bytes 8-15, part p=1).
__global__ __launch_bounds__(320) void qv_kernel(
    const u16* __restrict__ xh, const u16* __restrict__ xl,
    const u16* __restrict__ wqkh, const u16* __restrict__ wqkl,
    const u16* __restrict__ wvh, const u16* __restrict__ wvl,
    const float* __restrict__ bv,
    u16* __restrict__ Qh, u16* __restrict__ Ql,
    u16* __restrict__ Vph, u16* __restrict__ Vpl) {
  __shared__ float vt[4][2][16][17];
  int wave = threadIdx.x >> 6, lane = threadIdx.x & 63;  // wave 0..4
  int b = blockIdx.y;
  int n0 = blockIdx.x * 16;
  int col = lane & 15, g = lane >> 4;
  f32x4 acc[2] = {};
  const u16* xrh = xh + ((size_t)b * kN + n0 + col) * kC + g * 8;
  const u16* xrl = xl + ((size_t)b * kN + n0 + col) * kC + g * 8;
#pragma unroll
  for (int kk = 0; kk < 4; ++kk) {
    bf16x8 bh = *(const bf16x8*)(xrh + kk * 32);
    bf16x8 bl = *(const bf16x8*)(xrl + kk * 32);
#pragma unroll
    for (int i = 0; i < 2; ++i) {
      int ot = wave * 2 + i;
      size_t wi = (ot < 2) ? ((size_t)(ot * 16 + col) * kC) : ((size_t)((ot - 2) * 16 + col) * kC);
      const u16* wsh = (ot < 2) ? (wqkh + wi) : (wvh + wi);
      const u16* wsl = (ot < 2) ? (wqkl + wi) : (wvl + wi);
      bf16x8 ah = *(const bf16x8*)(wsh + kk * 32 + g * 8);
      bf16x8 al = *(const bf16x8*)(wsl + kk * 32 + g * 8);
      acc[i] = mfma3(ah, al, bh, bl, acc[i]);
    }
  }
  // stage V tiles (+bias) into per-wave LDS (producer order: [c16][n16])
  if (wave > 0) {
#pragma unroll
    for (int i = 0; i < 2; ++i) {
      int ct = wave * 2 + i - 2;
#pragma unroll
      for (int r = 0; r < 4; ++r)
        vt[wave - 1][i][4 * g + r][col] = acc[i][r] + bv[ct * 16 + 4 * g + r];
    }
  }
  __syncthreads();
  if (wave == 0) {
    // Q output (unchanged layout)
#pragma unroll
    for (int i = 0; i < 2; ++i) {
#pragma unroll
      for (int r = 0; r < 4; ++r) {
        int d = i * 16 + 4 * g + r;
        u16 hh, ll;
        split2(acc[i][r], hh, ll);
        size_t idx = ((size_t)b * kN + n0 + col) * kD + d;
        Qh[idx] = hh;
        Ql[idx] = ll;
      }
    }
  } else {
    // consumer-order read + split + packed write
    int nt = n0 >> 5, p = (n0 >> 4) & 1;
#pragma unroll
    for (int i = 0; i < 2; ++i) {
      int ct = wave * 2 + i - 2;
      bf16x4 vh4, vl4;
#pragma unroll
      for (int j = 0; j < 4; ++j) {
        float v = vt[wave - 1][i][col][4 * g + j];
        u16 hh, ll;
        split2(v, hh, ll);
        vh4[j] = (short)hh;
        vl4[j] = (short)ll;
      }
      size_t base = ((((size_t)b * (kN / 32) + nt) * 8 + ct) * 64 + lane) * 8 + p * 4;
      *(bf16x4*)(Vph + base) = vh4;
      *(bf16x4*)(Vpl + base) = vl4;
    }
  }
}

// ---------------- pass1: 4 waves split the m-loop; online merge via LDS
__global__ __launch_bounds__(256) void pass1_kernel(
    const u16* __restrict__ Qh, const u16* __restrict__ Ql,
    float* __restrict__ rm2, float* __restrict__ rinv) {
  __shared__ float mxs[4][16], sms[4][16];
  int wave = threadIdx.x >> 6, lane = threadIdx.x & 63;
  int b = blockIdx.y;
  int n0 = blockIdx.x * 16;
  int col = lane & 15, g = lane >> 4;
  const u16* qbh = Qh + (size_t)b * kN * kD;
  const u16* qbl = Ql + (size_t)b * kN * kD;
  bf16x8 ah = *(const bf16x8*)(qbh + (size_t)(n0 + col) * kD + g * 8);
  bf16x8 al = *(const bf16x8*)(qbl + (size_t)(n0 + col) * kD + g * 8);
  float mx[4] = {-3.0e38f, -3.0e38f, -3.0e38f, -3.0e38f};
  float sm[4] = {0.f, 0.f, 0.f, 0.f};
#pragma unroll 1
  for (int m0 = wave * 16; m0 < kN; m0 += 64) {
    bf16x8 bh = *(const bf16x8*)(qbh + (size_t)(m0 + col) * kD + g * 8);
    bf16x8 bl = *(const bf16x8*)(qbl + (size_t)(m0 + col) * kD + g * 8);
    f32x4 s = {};
    s = mfma3(ah, al, bh, bl, s);
#pragma unroll
    for (int r = 0; r < 4; ++r) {
      float nm = fmaxf(mx[r], s[r]);
      sm[r] = sm[r] * exp2f((mx[r] - nm) * kL2E) + exp2f((s[r] - nm) * kL2E);
      mx[r] = nm;
    }
  }
#pragma unroll
  for (int o = 1; o < 16; o <<= 1) {
#pragma unroll
    for (int r = 0; r < 4; ++r) {
      float Mo = __shfl_xor(mx[r], o, 64);
      float So = __shfl_xor(sm[r], o, 64);
      float nm = fmaxf(mx[r], Mo);
      sm[r] = sm[r] * exp2f((mx[r] - nm) * kL2E) + So * exp2f((Mo - nm) * kL2E);
      mx[r] = nm;
    }
  }
  if (col == 0) {
#pragma unroll
    for (int r = 0; r < 4; ++r) {
      mxs[wave][4 * g + r] = mx[r];
      sms[wave][4 * g + r] = sm[r];
    }
  }
  __syncthreads();
  if (threadIdx.x < 16) {
    int t = threadIdx.x;
    float M = mxs[0][t], S = sms[0][t];
#pragma unroll
    for (int w = 1; w < 4; ++w) {
      float Mo = mxs[w][t], So = sms[w][t];
      float nm = fmaxf(M, Mo);
      S = S * exp2f((M - nm) * kL2E) + So * exp2f((Mo - nm) * kL2E);
      M = nm;
    }
    rm2[(size_t)b * kN + n0 + t] = M * kL2E;
    rinv[(size_t)b * kN + n0 + t] = 1.0f / S;
  }
}

// ---------------- pass2: 4 waves split nn; packed-V coalesced loads; LDS combine
__global__ __launch_bounds__(256) void pass2_kernel(
    const u16* __restrict__ Qh, const u16* __restrict__ Ql,
    const u16* __restrict__ Vph, const u16* __restrict__ Vpl,
    const float* __restrict__ rm2, const float* __restrict__ rinv,
    const u16* __restrict__ xh, const u16* __restrict__ xl,
    u16* __restrict__ yth, u16* __restrict__ ytl) {
  __shared__ f32x4 accs[4][8][64];
  __shared__ float csl[4][16];
  int wave = threadIdx.x >> 6, lane = threadIdx.x & 63;
  int b = blockIdx.y;
  int m0 = blockIdx.x * 16;
  int col = lane & 15, g = lane >> 4;
  const u16* qbh = Qh + (size_t)b * kN * kD;
  const u16* qbl = Ql + (size_t)b * kN * kD;
  const float* rmb = rm2 + (size_t)b * kN;
  const float* rib = rinv + (size_t)b * kN;
  bf16x8 bmh = *(const bf16x8*)(qbh + (size_t)(m0 + col) * kD + g * 8);
  bf16x8 bml = *(const bf16x8*)(qbl + (size_t)(m0 + col) * kD + g * 8);
  const u16* vbh = Vph + (size_t)b * (kN / 32) * 8 * 64 * 8;
  const u16* vbl = Vpl + (size_t)b * (kN / 32) * 8 * 64 * 8;
  f32x4 acc[8] = {};
  float cs = 0.f;
#pragma unroll 1
  for (int nn = wave * 32; nn < kN; nn += 128) {
    bf16x8 ah0 = *(const bf16x8*)(qbh + (size_t)(nn + col) * kD + g * 8);
    bf16x8 al0 = *(const bf16x8*)(qbl + (size_t)(nn + col) * kD + g * 8);
    bf16x8 ah1 = *(const bf16x8*)(qbh + (size_t)(nn + 16 + col) * kD + g * 8);
    bf16x8 al1 = *(const bf16x8*)(qbl + (size_t)(nn + 16 + col) * kD + g * 8);
    f32x4 s0 = {}, s1 = {};
    s0 = mfma3(ah0, al0, bmh, bml, s0);
    s1 = mfma3(ah1, al1, bmh, bml, s1);
    bf16x8 b8h, b8l;
#pragma unroll
    for (int r = 0; r < 4; ++r) {
      float p0 = exp2f(s0[r] * kL2E - rmb[nn + 4 * g + r]) * rib[nn + 4 * g + r];
      float p1 = exp2f(s1[r] * kL2E - rmb[nn + 16 + 4 * g + r]) * rib[nn + 16 + 4 * g + r];
      cs += p0 + p1;
      u16 hh, ll;
      split2(p0, hh, ll);
      b8h[r] = (short)hh; b8l[r] = (short)ll;
      split2(p1, hh, ll);
      b8h[r + 4] = (short)hh; b8l[r + 4] = (short)ll;
    }
    size_t vtile = ((size_t)(nn >> 5) * 8) * 64 * 8;
#pragma unroll
    for (int ct = 0; ct < 8; ++ct) {
      size_t off = vtile + ((size_t)ct * 64 + lane) * 8;
      bf16x8 a8h = *(const bf16x8*)(vbh + off);
      bf16x8 a8l = *(const bf16x8*)(vbl + off);
      acc[ct] = mfma3(a8h, a8l, b8h, b8l, acc[ct]);
    }
  }
  cs += __shfl_xor(cs, 16, 64);
  cs += __shfl_xor(cs, 32, 64);
#pragma unroll
  for (int ct = 0; ct < 8; ++ct) accs[wave][ct][lane] = acc[ct];
  if (lane < 16) csl[wave][lane] = cs;
  __syncthreads();
  float csum = csl[0][col] + csl[1][col] + csl[2][col] + csl[3][col];
  float inv = 1.0f / (1e-9f + csum);
  const u16* xrh = xh + ((size_t)b * kN + m0 + col) * kC;
  const u16* xrl = xl + ((size_t)b * kN + m0 + col) * kC;
#pragma unroll
  for (int i = 0; i < 2; ++i) {
    int ct = wave * 2 + i;
    f32x4 a = accs[0][ct][lane];
    a += accs[1][ct][lane];
    a += accs[2][ct][lane];
    a += accs[3][ct][lane];
    bf16x4 xvh = *(const bf16x4*)(xrh + ct * 16 + 4 * g);
    bf16x4 xvl = *(const bf16x4*)(xrl + ct * 16 + 4 * g);
#pragma unroll
    for (int r = 0; r < 4; ++r) {
      float xv = bf2f((u16)xvh[r]) + bf2f((u16)xvl[r]);
      float y = xv - a[r] * inv;
      u16 hh, ll;
      split2(y, hh, ll);
      size_t idx = ((size_t)b * kN + m0 + col) * kC + ct * 16 + 4 * g + r;
      yth[idx] = hh;
      ytl[idx] = ll;
    }
  }
}

// ---------------- conv GEMM: 4 waves x 2 output-tiles, 16 n-cols per block
__global__ __launch_bounds__(256) void tconv_kernel(
    const u16* __restrict__ inh, const u16* __restrict__ inl,
    const u16* __restrict__ wh, const u16* __restrict__ wl,
    const float* __restrict__ bias, float* __restrict__ u,
    long ustride, long uoff) {
  int wave = threadIdx.x >> 6, lane = threadIdx.x & 63;
  int b = blockIdx.y;
  int n0 = blockIdx.x * 16;
  int col = lane & 15, g = lane >> 4;
  f32x4 acc[2] = {};
  const u16* xrh = inh + ((size_t)b * kN + n0 + col) * kC + g * 8;
  const u16* xrl = inl + ((size_t)b * kN + n0 + col) * kC + g * 8;
#pragma unroll
  for (int kk = 0; kk < 4; ++kk) {
    bf16x8 bh = *(const bf16x8*)(xrh + kk * 32);
    bf16x8 bl = *(const bf16x8*)(xrl + kk * 32);
#pragma unroll
    for (int i = 0; i < 2; ++i) {
      int ot = wave * 2 + i;
      bf16x8 ah = *(const bf16x8*)(wh + (size_t)(ot * 16 + col) * kC + kk * 32 + g * 8);
      bf16x8 al = *(const bf16x8*)(wl + (size_t)(ot * 16 + col) * kC + kk * 32 + g * 8);
      acc[i] = mfma3(ah, al, bh, bl, acc[i]);
    }
  }
#pragma unroll
  for (int i = 0; i < 2; ++i) {
    int ot = wave * 2 + i;
#pragma unroll
    for (int r = 0; r < 4; ++r) {
      int c = ot * 16 + 4 * g + r;
      float v = acc[i][r] + (bias ? bias[c] : 0.f);
      u[(size_t)b * ustride + uoff + (size_t)c * kN + n0 + col] = v;
    }
  }
}

// ---------------- BN stats, two-pass fp32 (u strided in d_out)
__global__ __launch_bounds__(256) void bn_stats_kernel(const float* __restrict__ u,
                                                       long ustride, long uoff,
                                                       float* __restrict__ stat) {
  int c = blockIdx.x;
  __shared__ float red[4];
  float s = 0.f;
  for (int i = threadIdx.x; i < kB * kN; i += 256) {
    int b = i >> 12, n = i & (kN - 1);
    s += u[(size_t)b * ustride + uoff + (size_t)c * kN + n];
  }
#pragma unroll
  for (int o = 1; o < 64; o <<= 1) s += __shfl_xor(s, o, 64);
  int wid = threadIdx.x >> 6, lane = threadIdx.x & 63;
  if (lane == 0) red[wid] = s;
  __syncthreads();
  float mean = (red[0] + red[1] + red[2] + red[3]) / (float)(kB * kN);
  __syncthreads();
  float ss = 0.f;
  for (int i = threadIdx.x; i < kB * kN; i += 256) {
    int b = i >> 12, n = i & (kN - 1);
    float d = u[(size_t)b * ustride + uoff + (size_t)c * kN + n] - mean;
    ss += d * d;
  }
#pragma unroll
  for (int o = 1; o < 64; o <<= 1) ss += __shfl_xor(ss, o, 64);
  if (lane == 0) red[wid] = ss;
  __syncthreads();
  if (threadIdx.x == 0) {
    float var = (red[0] + red[1] + red[2] + red[3]) / (float)(kB * kN);
    stat[c] = mean;
    stat[kC + c] = rsqrtf(var + 1e-5f);
  }
}

// ---------------- out = relu(BN(u)) [+ h + emb]; u strided (may alias out in-place)
__global__ __launch_bounds__(256) void bn_final_kernel(
    const float* __restrict__ u, long ustride, long uoff,
    const float* __restrict__ stat,
    const float* __restrict__ g, const float* __restrict__ bb,
    const float* __restrict__ h, long hstride, long hoff,
    const float* __restrict__ xyz, const float* __restrict__ pw,
    const float* __restrict__ pb, int use_res,
    float* __restrict__ out, long ostride, long ooff) {
  int n = blockIdx.x * 256 + threadIdx.x;
  int c = blockIdx.y;
  int b = blockIdx.z;
  float y = (u[(size_t)b * ustride + uoff + (size_t)c * kN + n] - stat[c]) * stat[kC + c] * g[c] + bb[c];
  y = fmaxf(y, 0.f);
  if (use_res) {
    const float* xp = xyz + ((size_t)b * kN + n) * 3;
    float e = pw[c * 3 + 0] * xp[0] + pw[c * 3 + 1] * xp[1] + pw[c * 3 + 2] * xp[2] + pb[c];
    y += h[(size_t)b * hstride + hoff + (size_t)c * kN + n] + e;
  }
  out[(size_t)b * ostride + ooff + (size_t)c * kN + n] = y;
}

extern "C" void kernel_launch(void* const* d_in, const int* in_sizes, int n_in,
                              void* d_out, int out_size, void* d_ws, size_t ws_size,
                              hipStream_t stream) {
  const float* x = (const float*)d_in[0];
  const float* xyz = (const float*)d_in[1];
  const float* conv1_w = (const float*)d_in[2];
  const float* bn1_g = (const float*)d_in[3];
  const float* bn1_b = (const float*)d_in[4];
  const float* pos_w = (const float*)d_in[5];
  const float* pos_b = (const float*)d_in[6];
  const float* sa_wqk = (const float*)d_in[7];
  const float* sa_wv = (const float*)d_in[8];
  const float* sa_bv = (const float*)d_in[9];
  const float* sa_wt = (const float*)d_in[10];
  const float* sa_bt = (const float*)d_in[11];
  const float* sa_bng = (const float*)d_in[12];
  const float* sa_bnb = (const float*)d_in[13];
  float* out = (float*)d_out;
  char* ws = (char*)d_ws;
  const size_t MB = (size_t)1 << 20;

  const size_t NEED = 28 * MB;
  if (ws_size < NEED) {
    float val = 100.0f + (float)(ws_size >> 20);
    sentinel_kernel<<<dim3((out_size + 255) / 256), dim3(256), 0, stream>>>(out, val, out_size);
    return;
  }

  // ws buffers — every region strictly write-before-read each call, NO aliasing
  u16* xh = (u16*)(ws);                  // [0,4MB)
  u16* xl = (u16*)(ws + 4 * MB);         // [4,8MB)
  u16* yth = (u16*)(ws + 8 * MB);        // [8,12MB)
  u16* ytl = (u16*)(ws + 12 * MB);       // [12,16MB)
  u16* Vph = (u16*)(ws + 16 * MB);       // [16,20MB)  packed V hi
  u16* Vpl = (u16*)(ws + 20 * MB);       // [20,24MB)  packed V lo
  u16* Qh = (u16*)(ws + 24 * MB);        // [24,25MB)
  u16* Ql = (u16*)(ws + 25 * MB);        // [25,26MB)
  u16* wa = (u16*)(ws + 26 * MB);        // weight split arena [26,27MB)
  size_t woff = 0;
  u16* c1h = wa + woff; woff += 16384;
  u16* c1l = wa + woff; woff += 16384;
  u16* qkh = wa + woff; woff += 5 * 32 * 128;
  u16* qkl = wa + woff; woff += 5 * 32 * 128;
  u16* wvh = wa + woff; woff += 5 * 128 * 128;
  u16* wvl = wa + woff; woff += 5 * 128 * 128;
  u16* wth = wa + woff; woff += 5 * 128 * 128;
  u16* wtl = wa + woff; woff += 5 * 128 * 128;
  float* rm2 = (float*)(ws + 27 * MB);
  float* rinv = (float*)(ws + 27 * MB + 65536);
  float* stat = (float*)(ws + 27 * MB + 131072);

  dim3 blk(256);

  cvt_split_kernel<<<dim3(64), blk, 0, stream>>>(conv1_w, c1h, c1l, 16384);
  cvt_split_kernel<<<dim3(80), blk, 0, stream>>>(sa_wqk, qkh, qkl, 20480);
  cvt_split_kernel<<<dim3(320), blk, 0, stream>>>(sa_wv, wvh, wvl, 81920);
  cvt_split_kernel<<<dim3(320), blk, 0, stream>>>(sa_wt, wth, wtl, 81920);

  const long sbo = (long)kCO * kN;
  const long slice = (long)kC * kN;
  const long h0off = 4 * slice;  // h0 parked in layer-4 slice (dead after layer-0 reads)

  // ---- setup: conv1 + BN + relu -> h0.  u lives in out slice 0 (dead after this).
  prep_kernel<<<dim3(kN / 32, kC / 32, kB), blk, 0, stream>>>(
      x, slice, 0, xyz, pos_w, pos_b, 0, xh, xl);
  tconv_kernel<<<dim3(kN / 16, kB), blk, 0, stream>>>(
      xh, xl, c1h, c1l, nullptr, out, sbo, 0);
  bn_stats_kernel<<<dim3(kC), blk, 0, stream>>>(out, sbo, 0, stat);
  bn_final_kernel<<<dim3(kN / 256, kC, kB), blk, 0, stream>>>(
      out, sbo, 0, stat, bn1_g, bn1_b, nullptr, 0, 0, xyz, pos_w, pos_b, 0,
      out, sbo, h0off);

  long hoff = h0off;
  for (int i = 0; i < kL; ++i) {
    long uoff = (long)i * slice;  // layer-i pre-BN u lives in out slice i (in-place BN)
    prep_kernel<<<dim3(kN / 32, kC / 32, kB), blk, 0, stream>>>(
        out, sbo, hoff, xyz, pos_w, pos_b, 1, xh, xl);
    qv_kernel<<<dim3(kN / 16, kB), dim3(320), 0, stream>>>(
        xh, xl, qkh + (size_t)i * kD * kC, qkl + (size_t)i * kD * kC,
        wvh + (size_t)i * kC * kC, wvl + (size_t)i * kC * kC,
        sa_bv + (size_t)i * kC, Qh, Ql, Vph, Vpl);
    pass1_kernel<<<dim3(kN / 16, kB), blk, 0, stream>>>(Qh, Ql, rm2, rinv);
    pass2_kernel<<<dim3(kN / 16, kB), blk, 0, stream>>>(
        Qh, Ql, Vph, Vpl, rm2, rinv, xh, xl, yth, ytl);
    tconv_kernel<<<dim3(kN / 16, kB), blk, 0, stream>>>(
        yth, ytl, wth + (size_t)i * kC * kC, wtl + (size_t)i * kC * kC,
        sa_bt + (size_t)i * kC, out, sbo, uoff);
    bn_stats_kernel<<<dim3(kC), blk, 0, stream>>>(out, sbo, uoff, stat);
    bn_final_kernel<<<dim3(kN / 256, kC, kB), blk, 0, stream>>>(
        out, sbo, uoff, stat, sa_bng + (size_t)i * kC, sa_bnb + (size_t)i * kC,
        out, sbo, hoff, xyz, pos_w, pos_b, 1, out, sbo, uoff);
    hoff = uoff;
  }
}